// Round 1
// baseline (553.187 us; speedup 1.0000x reference)
//
#include <hip/hip_runtime.h>
#include <hip/hip_bf16.h>

#define NNODES 50000
#define NEDGES 800000
#define NDIM   128
#define EDIM   64
#define K1     192   // NDIM + EDIM
#define K2     256   // 2*NDIM
#define NB     196   // ceil(NNODES/256) scan blocks

#define KP1 200      // LDS k-stride (shorts) for K=192 tile
#define KPA 136      // LDS k-stride for K=128
#define KPU 264      // LDS k-stride for K=256

typedef __attribute__((ext_vector_type(8))) short bf16x8;
typedef __attribute__((ext_vector_type(4))) short bf16x4;
typedef __attribute__((ext_vector_type(4))) float f32x4;

__device__ inline short f2bf(float f) {
  union { float f; unsigned u; } v; v.f = f;
  unsigned r = v.u + 0x7FFFu + ((v.u >> 16) & 1u);   // round-to-nearest-even
  return (short)(r >> 16);
}

__device__ inline bf16x4 pack4(float4 v) {
  bf16x4 p;
  p[0] = f2bf(v.x); p[1] = f2bf(v.y); p[2] = f2bf(v.z); p[3] = f2bf(v.w);
  return p;
}

// fp32 -> bf16 streaming convert (float4 per thread)
__global__ __launch_bounds__(256) void cvt_kernel(const float* __restrict__ src,
                                                  short* __restrict__ dst, int n) {
  int i = (blockIdx.x * 256 + threadIdx.x) * 4;
  if (i < n) {
    float4 v = *(const float4*)(src + i);
    *(bf16x4*)(dst + i) = pack4(v);
  }
}

// Transpose+convert fp32 weight [K][128] -> bf16 [n][K]
__global__ __launch_bounds__(256) void wt_kernel(const float* __restrict__ w,
                                                 short* __restrict__ wt, int K) {
  int i = blockIdx.x * 256 + threadIdx.x;
  if (i < K * NDIM) {
    int k = i >> 7;
    int n = i & 127;
    wt[n * K + k] = f2bf(w[i]);
  }
}

// ---- counting-sort pipeline: sort edges by src ----
__global__ __launch_bounds__(256) void hist_kernel(const int* __restrict__ eidx,
                                                   int* __restrict__ cnt) {
  int i = blockIdx.x * 256 + threadIdx.x;
  if (i < NEDGES) atomicAdd(&cnt[eidx[i]], 1);
}

__global__ __launch_bounds__(256) void scan_reduce_kernel(const int* __restrict__ cnt,
                                                          int* __restrict__ bsum) {
  __shared__ int sh[256];
  int tid = threadIdx.x;
  int i = blockIdx.x * 256 + tid;
  sh[tid] = (i < NNODES) ? cnt[i] : 0;
  __syncthreads();
#pragma unroll
  for (int off = 128; off > 0; off >>= 1) {
    if (tid < off) sh[tid] += sh[tid + off];
    __syncthreads();
  }
  if (tid == 0) bsum[blockIdx.x] = sh[0];
}

__global__ __launch_bounds__(256) void scan_top_kernel(const int* __restrict__ bsum,
                                                       int* __restrict__ bscan) {
  __shared__ int sh[256];
  int tid = threadIdx.x;
  int v = (tid < NB) ? bsum[tid] : 0;
  sh[tid] = v;
  __syncthreads();
#pragma unroll
  for (int off = 1; off < 256; off <<= 1) {
    int t = (tid >= off) ? sh[tid - off] : 0;
    __syncthreads();
    sh[tid] += t;
    __syncthreads();
  }
  bscan[tid] = sh[tid] - v;   // exclusive
}

__global__ __launch_bounds__(256) void scan_down_kernel(int* __restrict__ cnt,
                                                        const int* __restrict__ bscan,
                                                        int* __restrict__ row_ptr) {
  __shared__ int sh[256];
  int tid = threadIdx.x;
  int i = blockIdx.x * 256 + tid;
  int v = (i < NNODES) ? cnt[i] : 0;
  sh[tid] = v;
  __syncthreads();
#pragma unroll
  for (int off = 1; off < 256; off <<= 1) {
    int t = (tid >= off) ? sh[tid - off] : 0;
    __syncthreads();
    sh[tid] += t;
    __syncthreads();
  }
  if (i < NNODES) {
    row_ptr[i] = bscan[blockIdx.x] + (sh[tid] - v);
    cnt[i] = 0;                 // reset: becomes ticket counter, ends as degree
  }
}

__global__ __launch_bounds__(256) void permute_kernel(const int* __restrict__ eidx,
                                                      const int* __restrict__ row_ptr,
                                                      int* __restrict__ cnt,
                                                      int4* __restrict__ s_edges) {
  int e = blockIdx.x * 256 + threadIdx.x;
  if (e < NEDGES) {
    int s = eidx[e];
    int d = eidx[NEDGES + e];
    int pos = row_ptr[s] + atomicAdd(&cnt[s], 1);
    s_edges[pos] = make_int4(s, d, e, 0);
  }
}

// ---- edge kernel: h = lrelu(concat(nf_bf[dst], ef)@W1 + b1);
//      fragment-direct register run-aggregation (no LDS M tile, 2 barriers total).
//      A-row permutation: tile mt loads global row (m16>>2)*16 + mt*4 + (m16&3),
//      so each thread's output rows across mt are quad*16 .. quad*16+15 (contiguous
//      sorted edges) -> run-aggregate fully in registers, same atomic count as the
//      old LDS-strip scheme. LDS 26.4KB -> 6 blocks/CU. ----
__global__ __launch_bounds__(256, 6) void edge_kernel(const short* __restrict__ nf_bf,
                                                      const float* __restrict__ edge_feats,
                                                      const int4* __restrict__ s_edges,
                                                      const short* __restrict__ w1t,
                                                      const float* __restrict__ b1,
                                                      float* __restrict__ hagg) {
  __shared__ __align__(16) short X[64 * KP1];   // bf16 [64][KP1] = 25600 B
  __shared__ int srcs[64];
  __shared__ int dsts[64];
  __shared__ int eids[64];

  const int tid = threadIdx.x;
  const int e0 = blockIdx.x * 64;

  if (tid < 64) {
    int4 v = s_edges[e0 + tid];
    srcs[tid] = v.x;
    dsts[tid] = v.y;
    eids[tid] = v.z;
  }
  __syncthreads();

  // Stage: 4 threads/row; nf_bf[dst] (plain 16B copies) -> cols 0:128,
  //        edge_feats[eid] fp32->bf16 -> cols 128:192
  {
    int r = tid >> 2, q = tid & 3;
    const bf16x8* np = (const bf16x8*)(nf_bf + (size_t)dsts[r] * NDIM) + q * 4;
    const float4* ep = (const float4*)(edge_feats + (size_t)eids[r] * EDIM) + q * 4;
    short* dpn = X + r * KP1 + q * 32;
    short* dpe = X + r * KP1 + NDIM + q * 16;
#pragma unroll
    for (int j = 0; j < 4; ++j) *(bf16x8*)(dpn + j * 8) = np[j];
#pragma unroll
    for (int j = 0; j < 4; ++j) *(bf16x4*)(dpe + j * 4) = pack4(ep[j]);
  }
  __syncthreads();

  const int lane = tid & 63;
  const int wv = tid >> 6;
  const int m16 = lane & 15;
  const int quad = lane >> 4;
  // permuted A-row base: tile mt row m16 <- global row ar0 + mt*4
  const int ar0 = ((m16 >> 2) << 4) + (m16 & 3);

  f32x4 acc[4][2];
#pragma unroll
  for (int mt = 0; mt < 4; ++mt)
#pragma unroll
    for (int nt = 0; nt < 2; ++nt)
      acc[mt][nt] = (f32x4){0.f, 0.f, 0.f, 0.f};

#pragma unroll
  for (int ks = 0; ks < 6; ++ks) {
    const int k0 = ks * 32 + quad * 8;
    bf16x8 b[2];
#pragma unroll
    for (int nt = 0; nt < 2; ++nt) {
      int n = wv * 32 + nt * 16 + m16;
      b[nt] = *(const bf16x8*)(w1t + n * K1 + k0);
    }
#pragma unroll
    for (int mt = 0; mt < 4; ++mt) {
      bf16x8 a = *(const bf16x8*)(X + (ar0 + mt * 4) * KP1 + k0);
#pragma unroll
      for (int nt = 0; nt < 2; ++nt)
        acc[mt][nt] = __builtin_amdgcn_mfma_f32_16x16x32_bf16(a, b[nt], acc[mt][nt], 0, 0, 0);
    }
  }

  // Epilogue: thread owns rows rb..rb+15 (contiguous sorted edges) at 2 cols.
  // lrelu+bias then register run-aggregation -> atomics on run breaks.
  const int rb = quad << 4;
#pragma unroll
  for (int nt = 0; nt < 2; ++nt) {
    const int col = (wv << 5) + (nt << 4) + m16;
    const float bb = b1[col];
    float v[16];
#pragma unroll
    for (int mt = 0; mt < 4; ++mt)
#pragma unroll
      for (int i = 0; i < 4; ++i) {
        float t = acc[mt][nt][i] + bb;
        v[(mt << 2) + i] = t >= 0.f ? t : 0.2f * t;
      }
    float run = v[0];
    int prev = srcs[rb];
#pragma unroll
    for (int r = 1; r < 16; ++r) {
      int s = srcs[rb + r];
      if (s != prev) {
        atomicAdd(&hagg[(size_t)prev * NDIM + col], run);
        run = v[r];
        prev = s;
      } else {
        run += v[r];
      }
    }
    atomicAdd(&hagg[(size_t)prev * NDIM + col], run);
  }
}

// ---- node kernel: agg = hagg@W2 + deg*b2; out = lrelu(concat(x,agg)@U1+ub1)@U2+ub2 ----
__global__ __launch_bounds__(256) void node_kernel(const short* __restrict__ nf_bf,
                                                   const float* __restrict__ hagg,
                                                   const int* __restrict__ degc,
                                                   const short* __restrict__ w2t,
                                                   const float* __restrict__ b2,
                                                   const short* __restrict__ u1t,
                                                   const float* __restrict__ ub1,
                                                   const short* __restrict__ u2t,
                                                   const float* __restrict__ ub2,
                                                   float* __restrict__ out) {
  __shared__ __align__(16) short AGH[64 * KPA];   // phase1: hagg tile; phase3: h2 tile
  __shared__ __align__(16) short XU[64 * KPU];    // concat(x, agg) tile
  __shared__ float degs[64];

  const int tid = threadIdx.x;
  const int n0 = blockIdx.x * 64;

  if (tid < 64) {
    int node = n0 + tid;
    degs[tid] = (node < NNODES) ? (float)degc[node] : 0.f;
  }
  {
    int r = tid >> 2, q = tid & 3;
    int node = n0 + r; if (node >= NNODES) node = NNODES - 1;
    const float4* hp = (const float4*)(hagg + (size_t)node * NDIM) + q * 8;
    const bf16x8* xp = (const bf16x8*)(nf_bf + (size_t)node * NDIM) + q * 4;
    short* ap = AGH + r * KPA + q * 32;
    short* xq = XU + r * KPU + q * 32;
#pragma unroll
    for (int j = 0; j < 8; ++j) *(bf16x4*)(ap + j * 4) = pack4(hp[j]);
#pragma unroll
    for (int j = 0; j < 4; ++j) *(bf16x8*)(xq + j * 8) = xp[j];
  }
  __syncthreads();

  const int lane = tid & 63;
  const int wv = tid >> 6;
  const int m16 = lane & 15;
  const int quad = lane >> 4;

  f32x4 acc[4][2];

  // ---- GEMM-a: agg = AGH @ W2 (K=128) ----
#pragma unroll
  for (int mt = 0; mt < 4; ++mt)
#pragma unroll
    for (int nt = 0; nt < 2; ++nt)
      acc[mt][nt] = (f32x4){0.f, 0.f, 0.f, 0.f};
#pragma unroll
  for (int ks = 0; ks < 4; ++ks) {
    const int k0 = ks * 32 + quad * 8;
    bf16x8 b[2];
#pragma unroll
    for (int nt = 0; nt < 2; ++nt) {
      int n = wv * 32 + nt * 16 + m16;
      b[nt] = *(const bf16x8*)(w2t + n * NDIM + k0);
    }
#pragma unroll
    for (int mt = 0; mt < 4; ++mt) {
      bf16x8 a = *(const bf16x8*)(AGH + (mt * 16 + m16) * KPA + k0);
#pragma unroll
      for (int nt = 0; nt < 2; ++nt)
        acc[mt][nt] = __builtin_amdgcn_mfma_f32_16x16x32_bf16(a, b[nt], acc[mt][nt], 0, 0, 0);
    }
  }
#pragma unroll
  for (int nt = 0; nt < 2; ++nt) {
    int col = wv * 32 + nt * 16 + m16;
    float bb = b2[col];
#pragma unroll
    for (int mt = 0; mt < 4; ++mt) {
#pragma unroll
      for (int i = 0; i < 4; ++i) {
        int row = mt * 16 + quad * 4 + i;
        float v = acc[mt][nt][i] + degs[row] * bb;
        XU[row * KPU + NDIM + col] = f2bf(v);
      }
    }
  }
  __syncthreads();

  // ---- GEMM-b: t = XU @ U1 (K=256), lrelu -> AGH ----
#pragma unroll
  for (int mt = 0; mt < 4; ++mt)
#pragma unroll
    for (int nt = 0; nt < 2; ++nt)
      acc[mt][nt] = (f32x4){0.f, 0.f, 0.f, 0.f};
#pragma unroll
  for (int ks = 0; ks < 8; ++ks) {
    const int k0 = ks * 32 + quad * 8;
    bf16x8 b[2];
#pragma unroll
    for (int nt = 0; nt < 2; ++nt) {
      int n = wv * 32 + nt * 16 + m16;
      b[nt] = *(const bf16x8*)(u1t + n * K2 + k0);
    }
#pragma unroll
    for (int mt = 0; mt < 4; ++mt) {
      bf16x8 a = *(const bf16x8*)(XU + (mt * 16 + m16) * KPU + k0);
#pragma unroll
      for (int nt = 0; nt < 2; ++nt)
        acc[mt][nt] = __builtin_amdgcn_mfma_f32_16x16x32_bf16(a, b[nt], acc[mt][nt], 0, 0, 0);
    }
  }
  __syncthreads();
#pragma unroll
  for (int nt = 0; nt < 2; ++nt) {
    int col = wv * 32 + nt * 16 + m16;
    float bb = ub1[col];
#pragma unroll
    for (int mt = 0; mt < 4; ++mt) {
#pragma unroll
      for (int i = 0; i < 4; ++i) {
        int row = mt * 16 + quad * 4 + i;
        float v = acc[mt][nt][i] + bb;
        v = v >= 0.f ? v : 0.2f * v;
        AGH[row * KPA + col] = f2bf(v);
      }
    }
  }
  __syncthreads();

  // ---- GEMM-c: out = h2 @ U2 (K=128) + ub2 ----
#pragma unroll
  for (int mt = 0; mt < 4; ++mt)
#pragma unroll
    for (int nt = 0; nt < 2; ++nt)
      acc[mt][nt] = (f32x4){0.f, 0.f, 0.f, 0.f};
#pragma unroll
  for (int ks = 0; ks < 4; ++ks) {
    const int k0 = ks * 32 + quad * 8;
    bf16x8 b[2];
#pragma unroll
    for (int nt = 0; nt < 2; ++nt) {
      int n = wv * 32 + nt * 16 + m16;
      b[nt] = *(const bf16x8*)(u2t + n * NDIM + k0);
    }
#pragma unroll
    for (int mt = 0; mt < 4; ++mt) {
      bf16x8 a = *(const bf16x8*)(AGH + (mt * 16 + m16) * KPA + k0);
#pragma unroll
      for (int nt = 0; nt < 2; ++nt)
        acc[mt][nt] = __builtin_amdgcn_mfma_f32_16x16x32_bf16(a, b[nt], acc[mt][nt], 0, 0, 0);
    }
  }
#pragma unroll
  for (int nt = 0; nt < 2; ++nt) {
    int col = wv * 32 + nt * 16 + m16;
    float bb = ub2[col];
#pragma unroll
    for (int mt = 0; mt < 4; ++mt) {
#pragma unroll
      for (int i = 0; i < 4; ++i) {
        int row = mt * 16 + quad * 4 + i;
        int node = n0 + row;
        if (node < NNODES)
          out[(size_t)node * NDIM + col] = acc[mt][nt][i] + bb;
      }
    }
  }
}

extern "C" void kernel_launch(void* const* d_in, const int* in_sizes, int n_in,
                              void* d_out, int out_size, void* d_ws, size_t ws_size,
                              hipStream_t stream) {
  const float* node_feats = (const float*)d_in[0];
  const float* edge_feats = (const float*)d_in[1];
  const float* msg_w1 = (const float*)d_in[2];
  const float* msg_b1 = (const float*)d_in[3];
  const float* msg_w2 = (const float*)d_in[4];
  const float* msg_b2 = (const float*)d_in[5];
  const float* upd_w1 = (const float*)d_in[6];
  const float* upd_b1 = (const float*)d_in[7];
  const float* upd_w2 = (const float*)d_in[8];
  const float* upd_b2 = (const float*)d_in[9];
  const int* eidx = (const int*)d_in[10];

  // ws layout (16B-aligned sections)
  float* hagg   = (float*)d_ws;                        // N*128 f32
  int* cnt      = (int*)(hagg + (size_t)NNODES * NDIM);// N (zeroed with hagg)
  int* row_ptr  = cnt + NNODES;                        // N
  int* bsum     = row_ptr + NNODES;                    // 256
  int* bscan    = bsum + 256;                          // 256
  int4* s_edges = (int4*)(bscan + 256);                // E int4
  short* w1t    = (short*)(s_edges + NEDGES);          // 128*K1 bf16
  short* w2t    = w1t + 128 * K1;
  short* u1t    = w2t + 128 * 128;
  short* u2t    = u1t + 128 * K2;
  short* nf_bf  = u2t + 128 * 128;                     // N*128 bf16

  hipMemsetAsync(d_ws, 0, (size_t)(NNODES * NDIM + NNODES) * sizeof(float), stream);

  cvt_kernel<<<(NNODES * NDIM / 4 + 255) / 256, 256, 0, stream>>>(node_feats, nf_bf,
                                                                  NNODES * NDIM);
  wt_kernel<<<(K1 * 128) / 256, 256, 0, stream>>>(msg_w1, w1t, K1);
  wt_kernel<<<(128 * 128) / 256, 256, 0, stream>>>(msg_w2, w2t, 128);
  wt_kernel<<<(K2 * 128) / 256, 256, 0, stream>>>(upd_w1, u1t, K2);
  wt_kernel<<<(128 * 128) / 256, 256, 0, stream>>>(upd_w2, u2t, 128);

  hist_kernel<<<NEDGES / 256, 256, 0, stream>>>(eidx, cnt);
  scan_reduce_kernel<<<NB, 256, 0, stream>>>(cnt, bsum);
  scan_top_kernel<<<1, 256, 0, stream>>>(bsum, bscan);
  scan_down_kernel<<<NB, 256, 0, stream>>>(cnt, bscan, row_ptr);
  permute_kernel<<<NEDGES / 256, 256, 0, stream>>>(eidx, row_ptr, cnt, s_edges);

  edge_kernel<<<NEDGES / 64, 256, 0, stream>>>(nf_bf, edge_feats, s_edges,
                                               w1t, msg_b1, hagg);
  node_kernel<<<(NNODES + 63) / 64, 256, 0, stream>>>(nf_bf, hagg, cnt,
                                                      w2t, msg_b2, u1t, upd_b1,
                                                      u2t, upd_b2, (float*)d_out);
}

// Round 2
// 530.219 us; speedup vs baseline: 1.0433x; 1.0433x over previous
//
#include <hip/hip_runtime.h>
#include <hip/hip_bf16.h>

#define NNODES 50000
#define NEDGES 800000
#define NDIM   128
#define EDIM   64
#define K1     192   // NDIM + EDIM
#define K2     256   // 2*NDIM
#define NB     196   // ceil(NNODES/256) scan blocks

#define KP1 200      // LDS k-stride (shorts) for K=192 tile
#define KPA 136      // LDS k-stride for K=128
#define KPU 264      // LDS k-stride for K=256
#define MSTR 132     // LDS col-stride (floats) for 32-row message tile

typedef __attribute__((ext_vector_type(8))) short bf16x8;
typedef __attribute__((ext_vector_type(4))) short bf16x4;
typedef __attribute__((ext_vector_type(4))) float f32x4;

__device__ inline short f2bf(float f) {
  union { float f; unsigned u; } v; v.f = f;
  unsigned r = v.u + 0x7FFFu + ((v.u >> 16) & 1u);   // round-to-nearest-even
  return (short)(r >> 16);
}

__device__ inline bf16x4 pack4(float4 v) {
  bf16x4 p;
  p[0] = f2bf(v.x); p[1] = f2bf(v.y); p[2] = f2bf(v.z); p[3] = f2bf(v.w);
  return p;
}

// fp32 -> bf16 streaming convert (float4 per thread)
__global__ __launch_bounds__(256) void cvt_kernel(const float* __restrict__ src,
                                                  short* __restrict__ dst, int n) {
  int i = (blockIdx.x * 256 + threadIdx.x) * 4;
  if (i < n) {
    float4 v = *(const float4*)(src + i);
    *(bf16x4*)(dst + i) = pack4(v);
  }
}

// Transpose+convert all 4 fp32 weights [K][128] -> bf16 [n][K] in one launch
__global__ __launch_bounds__(256) void wt_all_kernel(const float* __restrict__ w1,
                                                     const float* __restrict__ w2,
                                                     const float* __restrict__ u1,
                                                     const float* __restrict__ u2,
                                                     short* __restrict__ w1t,
                                                     short* __restrict__ w2t,
                                                     short* __restrict__ u1t,
                                                     short* __restrict__ u2t) {
  int i = blockIdx.x * 256 + threadIdx.x;
  // segment bounds (elements): w1 192*128, w2 128*128, u1 256*128, u2 128*128
  const int A0 = K1 * 128;          // 24576
  const int A1 = A0 + 128 * 128;    // 40960
  const int A2 = A1 + K2 * 128;     // 73728
  const int A3 = A2 + 128 * 128;    // 90112
  if (i < A0) {
    int j = i, k = j >> 7, n = j & 127;
    w1t[n * K1 + k] = f2bf(w1[j]);
  } else if (i < A1) {
    int j = i - A0, k = j >> 7, n = j & 127;
    w2t[n * NDIM + k] = f2bf(w2[j]);
  } else if (i < A2) {
    int j = i - A1, k = j >> 7, n = j & 127;
    u1t[n * K2 + k] = f2bf(u1[j]);
  } else if (i < A3) {
    int j = i - A2, k = j >> 7, n = j & 127;
    u2t[n * NDIM + k] = f2bf(u2[j]);
  }
}

// ---- counting-sort pipeline: sort edges by src ----
__global__ __launch_bounds__(256) void hist_kernel(const int* __restrict__ eidx,
                                                   int* __restrict__ cnt) {
  int i = blockIdx.x * 256 + threadIdx.x;
  if (i < NEDGES) atomicAdd(&cnt[eidx[i]], 1);
}

__global__ __launch_bounds__(256) void scan_reduce_kernel(const int* __restrict__ cnt,
                                                          int* __restrict__ bsum) {
  __shared__ int sh[256];
  int tid = threadIdx.x;
  int i = blockIdx.x * 256 + tid;
  sh[tid] = (i < NNODES) ? cnt[i] : 0;
  __syncthreads();
#pragma unroll
  for (int off = 128; off > 0; off >>= 1) {
    if (tid < off) sh[tid] += sh[tid + off];
    __syncthreads();
  }
  if (tid == 0) bsum[blockIdx.x] = sh[0];
}

__global__ __launch_bounds__(256) void scan_top_kernel(const int* __restrict__ bsum,
                                                       int* __restrict__ bscan) {
  __shared__ int sh[256];
  int tid = threadIdx.x;
  int v = (tid < NB) ? bsum[tid] : 0;
  sh[tid] = v;
  __syncthreads();
#pragma unroll
  for (int off = 1; off < 256; off <<= 1) {
    int t = (tid >= off) ? sh[tid - off] : 0;
    __syncthreads();
    sh[tid] += t;
    __syncthreads();
  }
  bscan[tid] = sh[tid] - v;   // exclusive
}

__global__ __launch_bounds__(256) void scan_down_kernel(int* __restrict__ cnt,
                                                        const int* __restrict__ bscan,
                                                        int* __restrict__ row_ptr) {
  __shared__ int sh[256];
  int tid = threadIdx.x;
  int i = blockIdx.x * 256 + tid;
  int v = (i < NNODES) ? cnt[i] : 0;
  sh[tid] = v;
  __syncthreads();
#pragma unroll
  for (int off = 1; off < 256; off <<= 1) {
    int t = (tid >= off) ? sh[tid - off] : 0;
    __syncthreads();
    sh[tid] += t;
    __syncthreads();
  }
  if (i < NNODES) {
    row_ptr[i] = bscan[blockIdx.x] + (sh[tid] - v);
    cnt[i] = 0;                 // reset: becomes ticket counter, ends as degree
  }
}

__global__ __launch_bounds__(256) void permute_kernel(const int* __restrict__ eidx,
                                                      const int* __restrict__ row_ptr,
                                                      int* __restrict__ cnt,
                                                      int4* __restrict__ s_edges) {
  int e = blockIdx.x * 256 + threadIdx.x;
  if (e < NEDGES) {
    int s = eidx[e];
    int d = eidx[NEDGES + e];
    int pos = row_ptr[s] + atomicAdd(&cnt[s], 1);
    s_edges[pos] = make_int4(s, d, e, 0);
  }
}

// ---- edge kernel: h = lrelu(concat(nf_bf[dst], ef)@W1 + b1);
//      LDS-strip run-aggregated scatter (wave-uniform rows -> no divergence,
//      128-lane contiguous atomic bursts). Staging reads s_edges directly
//      (4 lanes share one 16B line -> merged) so no pre-stage barrier.
//      LDS 25.9KB -> 6 blocks/CU. ----
__global__ __launch_bounds__(256, 6) void edge_kernel(const short* __restrict__ nf_bf,
                                                      const float* __restrict__ edge_feats,
                                                      const int4* __restrict__ s_edges,
                                                      const short* __restrict__ w1t,
                                                      const float* __restrict__ b1,
                                                      float* __restrict__ hagg) {
  __shared__ __align__(16) char SH[64 * KP1 * 2];    // 25600 B: X tile, then M (32x132 fp32)
  __shared__ int srcs[64];

  short* X = (short*)SH;     // bf16 [64][KP1]
  float* M = (float*)SH;     // fp32 [32][MSTR] = 16896 B (aliased after X dead)

  const int tid = threadIdx.x;
  const int e0 = blockIdx.x * 64;

  // Stage: 4 threads/row read own edge record; nf_bf[dst] (plain 16B copies)
  //        -> cols 0:128, edge_feats[eid] fp32->bf16 -> cols 128:192.
  {
    int r = tid >> 2, q = tid & 3;
    int4 v = s_edges[e0 + r];           // 4 adjacent lanes share this 16B line
    if (q == 0) srcs[r] = v.x;          // consumed only after post-MFMA barrier
    const bf16x8* np = (const bf16x8*)(nf_bf + (size_t)v.y * NDIM) + q * 4;
    const float4* ep = (const float4*)(edge_feats + (size_t)v.z * EDIM) + q * 4;
    short* dpn = X + r * KP1 + q * 32;
    short* dpe = X + r * KP1 + NDIM + q * 16;
#pragma unroll
    for (int j = 0; j < 4; ++j) *(bf16x8*)(dpn + j * 8) = np[j];
#pragma unroll
    for (int j = 0; j < 4; ++j) *(bf16x4*)(dpe + j * 4) = pack4(ep[j]);
  }
  __syncthreads();

  const int lane = tid & 63;
  const int wv = tid >> 6;
  const int m16 = lane & 15;
  const int quad = lane >> 4;

  f32x4 acc[4][2];
#pragma unroll
  for (int mt = 0; mt < 4; ++mt)
#pragma unroll
    for (int nt = 0; nt < 2; ++nt)
      acc[mt][nt] = (f32x4){0.f, 0.f, 0.f, 0.f};

#pragma unroll
  for (int ks = 0; ks < 6; ++ks) {
    const int k0 = ks * 32 + quad * 8;
    bf16x8 b[2];
#pragma unroll
    for (int nt = 0; nt < 2; ++nt) {
      int n = wv * 32 + nt * 16 + m16;
      b[nt] = *(const bf16x8*)(w1t + n * K1 + k0);
    }
#pragma unroll
    for (int mt = 0; mt < 4; ++mt) {
      bf16x8 a = *(const bf16x8*)(X + (mt * 16 + m16) * KP1 + k0);
#pragma unroll
      for (int nt = 0; nt < 2; ++nt)
        acc[mt][nt] = __builtin_amdgcn_mfma_f32_16x16x32_bf16(a, b[nt], acc[mt][nt], 0, 0, 0);
    }
  }
  __syncthreads();   // all X reads done before M overwrites it

  // Two 32-row halves: epilogue -> M, then 256-thread run-aggregated scatter
#pragma unroll
  for (int h = 0; h < 2; ++h) {
#pragma unroll
    for (int nt = 0; nt < 2; ++nt) {
      int col = wv * 32 + nt * 16 + m16;
      float bb = b1[col];
#pragma unroll
      for (int mt2 = 0; mt2 < 2; ++mt2) {
        int mt = h * 2 + mt2;
#pragma unroll
        for (int i = 0; i < 4; ++i) {
          float v = acc[mt][nt][i] + bb;
          v = v >= 0.f ? v : 0.2f * v;
          int lr = mt2 * 16 + quad * 4 + i;
          M[lr * MSTR + col] = v;
        }
      }
    }
    __syncthreads();
    {
      const int c = tid & 127;
      const int lr0 = (tid >> 7) * 16;      // 16-row strip
      const int g0 = h * 32 + lr0;
      float a = M[lr0 * MSTR + c];
      int prev = srcs[g0];
#pragma unroll 4
      for (int r = 1; r < 16; ++r) {
        int s = srcs[g0 + r];
        float v = M[(lr0 + r) * MSTR + c];
        if (s != prev) {
          atomicAdd(&hagg[(size_t)prev * NDIM + c], a);
          a = v;
          prev = s;
        } else {
          a += v;
        }
      }
      atomicAdd(&hagg[(size_t)prev * NDIM + c], a);
    }
    if (h == 0) __syncthreads();   // M reused by second half
  }
}

// ---- node kernel: agg = hagg@W2 + deg*b2; out = lrelu(concat(x,agg)@U1+ub1)@U2+ub2
//      32-row tiles: LDS 25.7KB -> 6 blocks/CU (was 3), halved per-block chain ----
__global__ __launch_bounds__(256) void node_kernel(const short* __restrict__ nf_bf,
                                                   const float* __restrict__ hagg,
                                                   const int* __restrict__ degc,
                                                   const short* __restrict__ w2t,
                                                   const float* __restrict__ b2,
                                                   const short* __restrict__ u1t,
                                                   const float* __restrict__ ub1,
                                                   const short* __restrict__ u2t,
                                                   const float* __restrict__ ub2,
                                                   float* __restrict__ out) {
  __shared__ __align__(16) short AGH[32 * KPA];   // phase1: hagg tile; phase3: h2 tile
  __shared__ __align__(16) short XU[32 * KPU];    // concat(x, agg) tile
  __shared__ float degs[32];

  const int tid = threadIdx.x;
  const int n0 = blockIdx.x * 32;

  if (tid < 32) {
    int node = n0 + tid;
    degs[tid] = (node < NNODES) ? (float)degc[node] : 0.f;
  }
  {
    int r = tid >> 3, q = tid & 7;
    int node = n0 + r; if (node >= NNODES) node = NNODES - 1;
    const float4* hp = (const float4*)(hagg + (size_t)node * NDIM) + q * 4;
    const bf16x8* xp = (const bf16x8*)(nf_bf + (size_t)node * NDIM) + q * 2;
    short* ap = AGH + r * KPA + q * 16;
    short* xq = XU + r * KPU + q * 16;
#pragma unroll
    for (int j = 0; j < 4; ++j) *(bf16x4*)(ap + j * 4) = pack4(hp[j]);
#pragma unroll
    for (int j = 0; j < 2; ++j) *(bf16x8*)(xq + j * 8) = xp[j];
  }
  __syncthreads();

  const int lane = tid & 63;
  const int wv = tid >> 6;
  const int m16 = lane & 15;
  const int quad = lane >> 4;

  f32x4 acc[2][2];

  // ---- GEMM-a: agg = AGH @ W2 (K=128) ----
#pragma unroll
  for (int mt = 0; mt < 2; ++mt)
#pragma unroll
    for (int nt = 0; nt < 2; ++nt)
      acc[mt][nt] = (f32x4){0.f, 0.f, 0.f, 0.f};
#pragma unroll
  for (int ks = 0; ks < 4; ++ks) {
    const int k0 = ks * 32 + quad * 8;
    bf16x8 b[2];
#pragma unroll
    for (int nt = 0; nt < 2; ++nt) {
      int n = wv * 32 + nt * 16 + m16;
      b[nt] = *(const bf16x8*)(w2t + n * NDIM + k0);
    }
#pragma unroll
    for (int mt = 0; mt < 2; ++mt) {
      bf16x8 a = *(const bf16x8*)(AGH + (mt * 16 + m16) * KPA + k0);
#pragma unroll
      for (int nt = 0; nt < 2; ++nt)
        acc[mt][nt] = __builtin_amdgcn_mfma_f32_16x16x32_bf16(a, b[nt], acc[mt][nt], 0, 0, 0);
    }
  }
#pragma unroll
  for (int nt = 0; nt < 2; ++nt) {
    int col = wv * 32 + nt * 16 + m16;
    float bb = b2[col];
#pragma unroll
    for (int mt = 0; mt < 2; ++mt) {
#pragma unroll
      for (int i = 0; i < 4; ++i) {
        int row = mt * 16 + quad * 4 + i;
        float v = acc[mt][nt][i] + degs[row] * bb;
        XU[row * KPU + NDIM + col] = f2bf(v);
      }
    }
  }
  __syncthreads();

  // ---- GEMM-b: t = XU @ U1 (K=256), lrelu -> AGH ----
#pragma unroll
  for (int mt = 0; mt < 2; ++mt)
#pragma unroll
    for (int nt = 0; nt < 2; ++nt)
      acc[mt][nt] = (f32x4){0.f, 0.f, 0.f, 0.f};
#pragma unroll
  for (int ks = 0; ks < 8; ++ks) {
    const int k0 = ks * 32 + quad * 8;
    bf16x8 b[2];
#pragma unroll
    for (int nt = 0; nt < 2; ++nt) {
      int n = wv * 32 + nt * 16 + m16;
      b[nt] = *(const bf16x8*)(u1t + n * K2 + k0);
    }
#pragma unroll
    for (int mt = 0; mt < 2; ++mt) {
      bf16x8 a = *(const bf16x8*)(XU + (mt * 16 + m16) * KPU + k0);
#pragma unroll
      for (int nt = 0; nt < 2; ++nt)
        acc[mt][nt] = __builtin_amdgcn_mfma_f32_16x16x32_bf16(a, b[nt], acc[mt][nt], 0, 0, 0);
    }
  }
  __syncthreads();
#pragma unroll
  for (int nt = 0; nt < 2; ++nt) {
    int col = wv * 32 + nt * 16 + m16;
    float bb = ub1[col];
#pragma unroll
    for (int mt = 0; mt < 2; ++mt) {
#pragma unroll
      for (int i = 0; i < 4; ++i) {
        int row = mt * 16 + quad * 4 + i;
        float v = acc[mt][nt][i] + bb;
        v = v >= 0.f ? v : 0.2f * v;
        AGH[row * KPA + col] = f2bf(v);
      }
    }
  }
  __syncthreads();

  // ---- GEMM-c: out = h2 @ U2 (K=128) + ub2 ----
#pragma unroll
  for (int mt = 0; mt < 2; ++mt)
#pragma unroll
    for (int nt = 0; nt < 2; ++nt)
      acc[mt][nt] = (f32x4){0.f, 0.f, 0.f, 0.f};
#pragma unroll
  for (int ks = 0; ks < 4; ++ks) {
    const int k0 = ks * 32 + quad * 8;
    bf16x8 b[2];
#pragma unroll
    for (int nt = 0; nt < 2; ++nt) {
      int n = wv * 32 + nt * 16 + m16;
      b[nt] = *(const bf16x8*)(u2t + n * NDIM + k0);
    }
#pragma unroll
    for (int mt = 0; mt < 2; ++mt) {
      bf16x8 a = *(const bf16x8*)(AGH + (mt * 16 + m16) * KPA + k0);
#pragma unroll
      for (int nt = 0; nt < 2; ++nt)
        acc[mt][nt] = __builtin_amdgcn_mfma_f32_16x16x32_bf16(a, b[nt], acc[mt][nt], 0, 0, 0);
    }
  }
#pragma unroll
  for (int nt = 0; nt < 2; ++nt) {
    int col = wv * 32 + nt * 16 + m16;
    float bb = ub2[col];
#pragma unroll
    for (int mt = 0; mt < 2; ++mt) {
#pragma unroll
      for (int i = 0; i < 4; ++i) {
        int row = mt * 16 + quad * 4 + i;
        int node = n0 + row;
        if (node < NNODES)
          out[(size_t)node * NDIM + col] = acc[mt][nt][i] + bb;
      }
    }
  }
}

extern "C" void kernel_launch(void* const* d_in, const int* in_sizes, int n_in,
                              void* d_out, int out_size, void* d_ws, size_t ws_size,
                              hipStream_t stream) {
  const float* node_feats = (const float*)d_in[0];
  const float* edge_feats = (const float*)d_in[1];
  const float* msg_w1 = (const float*)d_in[2];
  const float* msg_b1 = (const float*)d_in[3];
  const float* msg_w2 = (const float*)d_in[4];
  const float* msg_b2 = (const float*)d_in[5];
  const float* upd_w1 = (const float*)d_in[6];
  const float* upd_b1 = (const float*)d_in[7];
  const float* upd_w2 = (const float*)d_in[8];
  const float* upd_b2 = (const float*)d_in[9];
  const int* eidx = (const int*)d_in[10];

  // ws layout (16B-aligned sections)
  float* hagg   = (float*)d_ws;                        // N*128 f32
  int* cnt      = (int*)(hagg + (size_t)NNODES * NDIM);// N (zeroed with hagg)
  int* row_ptr  = cnt + NNODES;                        // N
  int* bsum     = row_ptr + NNODES;                    // 256
  int* bscan    = bsum + 256;                          // 256
  int4* s_edges = (int4*)(bscan + 256);                // E int4
  short* w1t    = (short*)(s_edges + NEDGES);          // 128*K1 bf16
  short* w2t    = w1t + 128 * K1;
  short* u1t    = w2t + 128 * 128;
  short* u2t    = u1t + 128 * K2;
  short* nf_bf  = u2t + 128 * 128;                     // N*128 bf16

  hipMemsetAsync(d_ws, 0, (size_t)(NNODES * NDIM + NNODES) * sizeof(float), stream);

  cvt_kernel<<<(NNODES * NDIM / 4 + 255) / 256, 256, 0, stream>>>(node_feats, nf_bf,
                                                                  NNODES * NDIM);
  wt_all_kernel<<<(90112 + 255) / 256, 256, 0, stream>>>(msg_w1, msg_w2, upd_w1, upd_w2,
                                                         w1t, w2t, u1t, u2t);

  hist_kernel<<<NEDGES / 256, 256, 0, stream>>>(eidx, cnt);
  scan_reduce_kernel<<<NB, 256, 0, stream>>>(cnt, bsum);
  scan_top_kernel<<<1, 256, 0, stream>>>(bsum, bscan);
  scan_down_kernel<<<NB, 256, 0, stream>>>(cnt, bscan, row_ptr);
  permute_kernel<<<NEDGES / 256, 256, 0, stream>>>(eidx, row_ptr, cnt, s_edges);

  edge_kernel<<<NEDGES / 64, 256, 0, stream>>>(nf_bf, edge_feats, s_edges,
                                               w1t, msg_b1, hagg);
  node_kernel<<<(NNODES + 31) / 32, 256, 0, stream>>>(nf_bf, hagg, cnt,
                                                      w2t, msg_b2, u1t, upd_b1,
                                                      u2t, upd_b2, (float*)d_out);
}